// Round 13
// baseline (603.689 us; speedup 1.0000x reference)
//
#include <hip/hip_runtime.h>

typedef __attribute__((ext_vector_type(8))) short short8;
typedef __attribute__((ext_vector_type(4))) float f32x4;

__device__ __forceinline__ unsigned short f2b(float f){
  union { float f; unsigned u; } x; x.f = f;
  unsigned r = x.u + 0x7fffu + ((x.u >> 16) & 1u);
  return (unsigned short)(r >> 16);
}
__device__ __forceinline__ float b2f(unsigned short v){
  union { unsigned u; float f; } x; x.u = ((unsigned)v) << 16; return x.f;
}

// k-interleave permutation on 8B slots (rotation within each 8-slot/64B group):
// old slot t = S*8 + h*4 + kq  ->  new slot u = S*8 + kq*2 + h.
__device__ __forceinline__ int pslot(int t){
  return (t & ~7) | ((t & 3) << 1) | ((t >> 2) & 1);
}

// ---- fp8 e4m3 encode/decode (HW cvt if available) ----
__device__ __forceinline__ unsigned char enc1(float v){
#if __has_builtin(__builtin_amdgcn_cvt_pk_fp8_f32)
  return (unsigned char)(__builtin_amdgcn_cvt_pk_fp8_f32(v, v, 0, false) & 0xff);
#else
  union{float f;unsigned u;}x; x.f=v;
  unsigned s = x.u >> 31;
  float av = fabsf(v);
  if (av >= 448.f) return (unsigned char)((s<<7)|0x7e);
  if (av < 0.0078125f){ unsigned d=(unsigned)(av*512.f+0.5f); return (unsigned char)((s<<7)|d); }
  unsigned q = x.u & 0x7fffffff;
  q = q + 0x7ffff + ((q>>20)&1);
  int e2 = (int)(q>>23) - 127;
  unsigned m3 = (q>>20)&7;
  if (e2 < -6){ unsigned d=(unsigned)(av*512.f+0.5f); return (unsigned char)((s<<7)|d); }
  return (unsigned char)((s<<7) | ((unsigned)(e2+7)<<3) | m3);
#endif
}
__device__ __forceinline__ unsigned pk4(float a,float b,float c,float d){
#if __has_builtin(__builtin_amdgcn_cvt_pk_fp8_f32)
  int v = __builtin_amdgcn_cvt_pk_fp8_f32(a, b, 0, false);
  v = __builtin_amdgcn_cvt_pk_fp8_f32(c, d, v, true);
  return (unsigned)v;
#else
  return (unsigned)enc1(a) | ((unsigned)enc1(b)<<8) | ((unsigned)enc1(c)<<16) | ((unsigned)enc1(d)<<24);
#endif
}
__device__ __forceinline__ void dec4(unsigned u, float* o){
#if __has_builtin(__builtin_amdgcn_cvt_pk_f32_fp8)
  auto lo = __builtin_amdgcn_cvt_pk_f32_fp8((int)u, false);
  auto hi = __builtin_amdgcn_cvt_pk_f32_fp8((int)u, true);
  o[0]=lo[0]; o[1]=lo[1]; o[2]=hi[0]; o[3]=hi[1];
#else
  #pragma unroll
  for (int j=0;j<4;j++){
    unsigned b = (u >> (8*j)) & 0xffu;
    unsigned s = b >> 7, ex = (b >> 3) & 15u, mn = b & 7u;
    union{unsigned u;float f;} x;
    x.u = ex ? ((s<<31)|((ex+120u)<<23)|(mn<<20)) : (s<<31);
    o[j] = x.f;
  }
#endif
}

// ---------------- CSR build ----------------
__global__ void count_k(const int* __restrict__ dst, int* __restrict__ deg, int E){
  int e = blockIdx.x*256 + threadIdx.x;
  if (e < E) atomicAdd(&deg[dst[e]], 1);
}

__global__ void scan_k(const int* __restrict__ deg, int* __restrict__ rowstart,
                       int* __restrict__ cursor, int n)
{
  __shared__ int wsum[16];
  int tid = threadIdx.x, lane = tid & 63, wv = tid >> 6;
  int CH = (n + 1023) >> 10;
  int b0 = tid * CH; if (b0 > n) b0 = n;
  int bend = b0 + CH; if (bend > n) bend = n;
  int sum = 0;
  for (int i = b0; i < bend; ++i) sum += deg[i];
  int xs = sum;
  #pragma unroll
  for (int o=1;o<64;o<<=1){ int t = __shfl_up(xs, o, 64); if (lane >= o) xs += t; }
  if (lane == 63) wsum[wv] = xs;
  __syncthreads();
  if (tid < 16){
    int w = wsum[tid];
    #pragma unroll
    for (int o=1;o<16;o<<=1){ int t = __shfl_up(w, o, 64); if (tid >= o) w += t; }
    wsum[tid] = w;
  }
  __syncthreads();
  int off = (wv ? wsum[wv-1] : 0) + xs - sum;
  int run = off;
  for (int i = b0; i < bend; ++i){ rowstart[i] = run; cursor[i] = run; run += deg[i]; }
  if (b0 < n && bend == n) rowstart[n] = run;
  if (n == 0 && tid == 0) rowstart[0] = 0;
}

__global__ void fill_k(const int* __restrict__ src, const int* __restrict__ dst,
                       int* __restrict__ cursor, int* __restrict__ csrc, int E){
  int e = blockIdx.x*256 + threadIdx.x;
  if (e < E){
    int p = atomicAdd(&cursor[dst[e]], 1);
    csrc[p] = src[e];
  }
}

// ---------------- fused weight transposes -> fp8 (x64), k-permuted ----------------
__global__ void transpose_all_k(const float* __restrict__ Wq, const float* __restrict__ Wk,
  const float* __restrict__ Wv, const float* __restrict__ Ws,
  const float* __restrict__ W1, const float* __restrict__ W2,
  unsigned char* __restrict__ wtqkvs8, unsigned char* __restrict__ wt1_8,
  unsigned char* __restrict__ wt2_8)
{
  int bid = blockIdx.x;
  const float* src; unsigned char* dst; int r, c, lb;
  if (bid < 1024){
    int j = bid >> 7;        // 0..7
    int l = j >> 2, w = j & 3;
    src = (w==0?Wq : w==1?Wk : w==2?Wv : Ws) + (size_t)l*512*512;
    dst = wtqkvs8 + ((size_t)l*2048 + (size_t)w*512)*512;
    r = 512; c = 512; lb = bid & 127;
  } else if (bid < 1280){ src = W1; dst = wt1_8; r = 512; c = 1024; lb = bid - 1024; }
  else { src = W2; dst = wt2_8; r = 1024; c = 512; lb = bid - 1280; }
  int idx = lb*256 + threadIdx.x;
  int o = idx % c;
  int i0 = (idx / c) << 3;   // k-slot t = i0>>3
  float v[8];
  #pragma unroll
  for (int t=0;t<8;t++) v[t] = 64.f * src[(size_t)(i0+t)*c + o];
  unsigned lo = pk4(v[0],v[1],v[2],v[3]);
  unsigned hi = pk4(v[4],v[5],v[6],v[7]);
  *(unsigned long long*)&dst[(size_t)o*r + pslot(i0>>3)*8] =
      (unsigned long long)lo | ((unsigned long long)hi << 32);
}

// ---------------- f32 -> fp8 k-permuted (x for layer-1 GEMM) + bf16 (enc) ----------------
__global__ void cvt8_k(const float* __restrict__ in, unsigned char* __restrict__ out8,
                       unsigned short* __restrict__ outb, size_t n){
  size_t i = ((size_t)blockIdx.x*256 + threadIdx.x)*8;
  if (i >= n) return;
  const float4* p = (const float4*)(in + i);
  float4 a0 = p[0], a1 = p[1];
  short8 vv;
  ((unsigned short*)&vv)[0] = f2b(a0.x); ((unsigned short*)&vv)[1] = f2b(a0.y);
  ((unsigned short*)&vv)[2] = f2b(a0.z); ((unsigned short*)&vv)[3] = f2b(a0.w);
  ((unsigned short*)&vv)[4] = f2b(a1.x); ((unsigned short*)&vv)[5] = f2b(a1.y);
  ((unsigned short*)&vv)[6] = f2b(a1.z); ((unsigned short*)&vv)[7] = f2b(a1.w);
  *(short8*)&outb[i] = vv;
  unsigned lo = pk4(a0.x,a0.y,a0.z,a0.w);
  unsigned hi = pk4(a1.x,a1.y,a1.z,a1.w);
  size_t op = (i & ~(size_t)511) | ((size_t)pslot((int)((i & 511) >> 3)) << 3);
  *(unsigned long long*)&out8[op] = (unsigned long long)lo | ((unsigned long long)hi<<32);
}

// ---------------- unified fp8 GEMM: A8[M][KC] x Bt8[NN*128][KC], BK=128, k-permuted ----------------
// MF = M-fragments/wave: MF=8 -> BM=256 (48KB LDS), MF=4 -> BM=128 (32KB LDS).
// Single-buffer LDS, serial 2-barrier loop. Conflict-free b128 reads via k-interleave.
// MODE 0: QKVS (col<512: bf16 Q; 512..1535: fp8 KV; >=1536: bf16 S)
// MODE 1: FFN1 (bias + relu -> fp8 k-permuted outC[row][1024])
// MODE 2: FFN2 (bias + res -> f32 outF[row][512])
template<int MODE, int KC, int NN, int MF>
__global__ __launch_bounds__(256) void gemm8_k(
    const unsigned char* __restrict__ A8,
    const unsigned char* __restrict__ Bt8,
    int M,
    const float* __restrict__ bias0, const float* __restrict__ bias1,
    const float* __restrict__ bias2, const float* __restrict__ bias3,
    unsigned short* __restrict__ qb, unsigned short* __restrict__ skipb,
    unsigned char* __restrict__ outC,
    float* __restrict__ outF, const float* __restrict__ res)
{
  constexpr int BM = MF*32;
  __shared__ __align__(16) unsigned char lA[BM*128];
  __shared__ __align__(16) unsigned char lB[128*128];
  const int tid  = threadIdx.x;
  const int lane = tid & 63;
  const int wid  = tid >> 6;

  const int nwg = gridDim.x;
  int id = blockIdx.x;
  int q = nwg >> 3, r = nwg & 7;
  int xc = id & 7, yy = id >> 3;
  int swz = (xc < r ? xc*(q+1) : r*(q+1) + (xc-r)*q) + yy;
  const int bm = (swz / NN) * BM;
  const int bn = (swz % NN) * 128;
  const int wm = (wid >> 1) * (MF*16);
  const int wn = (wid & 1) * 64;

  f32x4 acc[MF][4];
  #pragma unroll
  for (int m=0;m<MF;m++)
    #pragma unroll
    for (int n=0;n<4;n++) acc[m][n] = (f32x4)0.f;

  const int kq = lane >> 4;          // 0..3 (k-quadrant)

  for (int kt = 0; kt < KC; kt += 128){
    #pragma unroll
    for (int it = 0; it < MF; ++it) {   // A tile: BM x 128
      int chunk = it*256 + tid;
      int row = chunk >> 3;
      int cin = chunk & 7;
      int scol = (cin ^ (row & 7)) * 16;
      int ga = bm + row; if (ga >= M) ga = M - 1;
      __builtin_amdgcn_global_load_lds(
        (const __attribute__((address_space(1))) void*)(A8 + (size_t)ga*KC + kt + scol),
        (__attribute__((address_space(3))) void*)(&lA[(it*256 + (wid<<6))*16]),
        16, 0, 0);
    }
    #pragma unroll
    for (int it = 0; it < 4; ++it) {    // B tile: 128 x 128
      int chunk = it*256 + tid;
      int row = chunk >> 3;
      int cin = chunk & 7;
      int scol = (cin ^ (row & 7)) * 16;
      __builtin_amdgcn_global_load_lds(
        (const __attribute__((address_space(1))) void*)(Bt8 + (size_t)(bn + row)*KC + kt + scol),
        (__attribute__((address_space(3))) void*)(&lB[(it*256 + (wid<<6))*16]),
        16, 0, 0);
    }
    __syncthreads();
    #pragma unroll
    for (int S = 0; S < 2; ++S){
      ulonglong2 af[MF], bfv[4];
      #pragma unroll
      for (int m=0;m<MF;m++){
        int rr = wm + m*16 + (lane & 15);
        int c  = (S*4 + kq) ^ (rr & 7);
        af[m] = *(const ulonglong2*)&lA[rr*128 + c*16];
      }
      #pragma unroll
      for (int n=0;n<4;n++){
        int rr = wn + n*16 + (lane & 15);
        int c  = (S*4 + kq) ^ (rr & 7);
        bfv[n] = *(const ulonglong2*)&lB[rr*128 + c*16];
      }
      #pragma unroll
      for (int m=0;m<MF;m++)
        #pragma unroll
        for (int n=0;n<4;n++){
          acc[m][n] = __builtin_amdgcn_mfma_f32_16x16x32_fp8_fp8(
              (long)af[m].x, (long)bfv[n].x, acc[m][n], 0,0,0);
          acc[m][n] = __builtin_amdgcn_mfma_f32_16x16x32_fp8_fp8(
              (long)af[m].y, (long)bfv[n].y, acc[m][n], 0,0,0);
        }
    }
    __syncthreads();
  }

  #pragma unroll
  for (int m=0;m<MF;m++){
    int row0 = bm + wm + m*16 + ((lane >> 4) << 2);
    #pragma unroll
    for (int n=0;n<4;n++){
      int col = bn + wn + n*16 + (lane & 15);
      float bval;
      if (MODE == 0){
        bval = (col < 512) ? bias0[col]
             : (col < 1024) ? bias1[col-512]
             : (col < 1536) ? bias2[col-1024] : bias3[col-1536];
      } else {
        bval = bias0[col];
      }
      #pragma unroll
      for (int r4=0;r4<4;r4++){
        int row = row0 + r4;
        if (row < M){
          float v = acc[m][n][r4] * 0.015625f + bval;   // /64 weight scale
          if (MODE == 0){
            if (col < 512)       qb[(size_t)row*512 + col] = f2b(v);
            else if (col < 1536) outC[(size_t)row*1024 + (col-512)] = enc1(v);
            else                 skipb[(size_t)row*512 + (col-1536)] = f2b(v);
          } else if (MODE == 1){
            v = fmaxf(v, 0.0f);
            int pc = (pslot(col >> 3) << 3) | (col & 7);
            outC[(size_t)row*1024 + pc] = enc1(v);
          } else {
            v += res[(size_t)row*512 + col];
            outF[(size_t)row*512 + col] = v;
          }
        }
      }
    }
  }
}

// ---------------- attention: one wave per node (static), no-max softmax, 2-deep prefetch ----------------
// OUT 0: write fp8 k-permuted x (layer-2 GEMM input).
// OUT 2: fused LN1 -> write f32 h (outF=skip) + fp8 k-permuted h8 (xout8).
template<int OUT>
__global__ __launch_bounds__(256) void attn_k(
  const unsigned short* __restrict__ qb, const unsigned char* __restrict__ kv8,
  const unsigned short* __restrict__ skipb, const unsigned short* __restrict__ encb,
  const int* __restrict__ rowstart, const int* __restrict__ csrc,
  float* __restrict__ xout, unsigned char* __restrict__ xout8,
  const float* __restrict__ lng, const float* __restrict__ lnb, int N)
{
  int n = blockIdx.x*4 + (threadIdx.x>>6);
  if (n >= N) return;
  int lane = threadIdx.x & 63;

  const short8 qv = *(const short8*)&qb[(size_t)n*512 + lane*8];
  size_t base = (size_t)n*512 + (size_t)lane*8;
  const short8 sv = *(const short8*)&skipb[base];
  const short8 ev = *(const short8*)&encb[base];
  float qf[8];
  #pragma unroll
  for (int j=0;j<8;j++) qf[j] = b2f(((const unsigned short*)&qv)[j]);

  float l = 0.f;
  float acc[8] = {0.f,0.f,0.f,0.f,0.f,0.f,0.f,0.f};
  int e = rowstart[n], e1 = rowstart[n+1];
  if (e < e1){
    int s0 = csrc[e];
    int s1 = (e+1 < e1) ? csrc[e+1] : s0;
    uint2 k0 = *(const uint2*)&kv8[(size_t)s0*1024 + lane*8];
    uint2 v0 = *(const uint2*)&kv8[(size_t)s0*1024 + 512 + lane*8];
    uint2 k1 = *(const uint2*)&kv8[(size_t)s1*1024 + lane*8];
    uint2 v1 = *(const uint2*)&kv8[(size_t)s1*1024 + 512 + lane*8];
    for (; e < e1; ++e){
      int s2 = (e+2 < e1) ? csrc[e+2] : s0;
      uint2 k2 = *(const uint2*)&kv8[(size_t)s2*1024 + lane*8];
      uint2 v2 = *(const uint2*)&kv8[(size_t)s2*1024 + 512 + lane*8];
      float kf[8]; dec4(k0.x, kf); dec4(k0.y, kf+4);
      float dot = 0.f;
      #pragma unroll
      for (int j=0;j<8;j++) dot += qf[j]*kf[j];
      dot += __shfl_xor(dot,1); dot += __shfl_xor(dot,2); dot += __shfl_xor(dot,4);
      float p = __expf(dot * 0.125f);     // 1/sqrt(64); no max shift (bounded logits)
      l += p;
      float vf[8]; dec4(v0.x, vf); dec4(v0.y, vf+4);
      #pragma unroll
      for (int j=0;j<8;j++) acc[j] += p*vf[j];
      k0 = k1; v0 = v1; k1 = k2; v1 = v2;
    }
  }
  float inv = 1.f/(l + 1e-16f);
  float o[8];
  #pragma unroll
  for (int j=0;j<8;j++)
    o[j] = acc[j]*inv + b2f(((const unsigned short*)&sv)[j]) + b2f(((const unsigned short*)&ev)[j]);

  if (OUT == 0){
    unsigned lo = pk4(o[0],o[1],o[2],o[3]);
    unsigned hi = pk4(o[4],o[5],o[6],o[7]);
    size_t op = (size_t)n*512 + ((size_t)pslot(lane) << 3);
    *(unsigned long long*)&xout8[op] = (unsigned long long)lo | ((unsigned long long)hi<<32);
  } else {
    // fused LayerNorm over the row held by this wave
    float s=0.f, ss=0.f;
    #pragma unroll
    for (int j=0;j<8;j++){ s += o[j]; ss += o[j]*o[j]; }
    #pragma unroll
    for (int w=1;w<64;w<<=1){ s += __shfl_xor(s,w); ss += __shfl_xor(ss,w); }
    float mean = s * (1.f/512.f);
    float var  = ss * (1.f/512.f) - mean*mean;
    float rstd = rsqrtf(var + 1e-5f);
    float h[8];
    #pragma unroll
    for (int j=0;j<8;j++){
      int c = lane*8 + j;
      h[j] = (o[j]-mean)*rstd*lng[c] + lnb[c];
    }
    float4* po = (float4*)&xout[base];
    po[0] = make_float4(h[0],h[1],h[2],h[3]);
    po[1] = make_float4(h[4],h[5],h[6],h[7]);
    unsigned lo = pk4(h[0],h[1],h[2],h[3]);
    unsigned hi = pk4(h[4],h[5],h[6],h[7]);
    size_t op = (size_t)n*512 + ((size_t)pslot(lane) << 3);
    *(unsigned long long*)&xout8[op] = (unsigned long long)lo | ((unsigned long long)hi<<32);
  }
}

// ---------------- LayerNorm (wave per row): f32 (ln + addv) -> outF ----------------
__global__ __launch_bounds__(256) void ln_k(const float* __restrict__ x,
  const float* __restrict__ g, const float* __restrict__ b,
  float* __restrict__ outF, const float* __restrict__ addv, int N)
{
  int n = blockIdx.x*4 + (threadIdx.x>>6);
  if (n >= N) return;
  int lane = threadIdx.x & 63;
  size_t base = (size_t)n*512 + (size_t)lane*8;
  const float4* p = (const float4*)(x + base);
  float4 a0 = p[0], a1 = p[1];
  float v[8] = {a0.x,a0.y,a0.z,a0.w,a1.x,a1.y,a1.z,a1.w};
  float s=0.f, ss=0.f;
  #pragma unroll
  for (int j=0;j<8;j++){ s += v[j]; ss += v[j]*v[j]; }
  #pragma unroll
  for (int o=1;o<64;o<<=1){ s += __shfl_xor(s,o); ss += __shfl_xor(ss,o); }
  float mean = s * (1.f/512.f);
  float var  = ss * (1.f/512.f) - mean*mean;
  float rstd = rsqrtf(var + 1e-5f);
  #pragma unroll
  for (int j=0;j<8;j++){
    int c = lane*8 + j;
    float o = (v[j]-mean)*rstd*g[c] + b[c];
    outF[base+j] = o + addv[base+j];
  }
}

extern "C" void kernel_launch(void* const* d_in, const int* in_sizes, int n_in,
                              void* d_out, int out_size, void* d_ws, size_t ws_size,
                              hipStream_t stream)
{
  const float* x0  = (const float*)d_in[0];
  const int*  eidx = (const int*)d_in[1];
  const float* Wq  = (const float*)d_in[4];
  const float* bq  = (const float*)d_in[5];
  const float* Wk  = (const float*)d_in[6];
  const float* bk  = (const float*)d_in[7];
  const float* Wv  = (const float*)d_in[8];
  const float* bv  = (const float*)d_in[9];
  const float* Wsk = (const float*)d_in[10];
  const float* bs  = (const float*)d_in[11];
  const float* W1  = (const float*)d_in[12];
  const float* b1  = (const float*)d_in[13];
  const float* W2  = (const float*)d_in[14];
  const float* b2  = (const float*)d_in[15];
  const float* lng = (const float*)d_in[16];
  const float* lnb = (const float*)d_in[17];

  const int N = in_sizes[0] / 512;
  const int E = in_sizes[1] / 2;
  const int* esrc = eidx;
  const int* edst = eidx + E;

  char* ws = (char*)d_ws;
  size_t off = 0;
  auto alloc = [&](size_t bytes)->char*{
    char* p = ws + off; off = (off + bytes + 255) & ~(size_t)255; return p;
  };
  unsigned char*  wtqkvs8 = (unsigned char*)alloc((size_t)2*2048*512);   // fp8 x64, k-perm
  unsigned char*  wt1_8   = (unsigned char*)alloc((size_t)1024*512);     // fp8 x64, k-perm
  unsigned char*  wt2_8   = (unsigned char*)alloc((size_t)512*1024);     // fp8 x64, k-perm
  unsigned short* qb      = (unsigned short*)alloc((size_t)N*512*2);     // Q bf16
  unsigned char*  kv8     = (unsigned char*)alloc((size_t)N*1024);       // K,V fp8 (natural)
  float*          skip    = (float*)alloc((size_t)N*512*4);              // f32 h after LN1
  float*          xbuf    = (float*)alloc((size_t)N*512*4);              // f32 y after FFN2
  unsigned char*  xb8     = (unsigned char*)alloc((size_t)N*512);        // fp8 x, k-perm
  unsigned short* encb    = (unsigned short*)alloc((size_t)N*512*2);     // bf16 enc
  unsigned short* skipb   = (unsigned short*)alloc((size_t)N*512*2);     // bf16 skip proj
  int* deg      = (int*)alloc((size_t)N*4);
  int* rowstart = (int*)alloc((size_t)(N+1)*4);
  int* cursor   = (int*)alloc((size_t)N*4);
  int* csrc     = (int*)alloc((size_t)E*4);
  unsigned char* t8 = (unsigned char*)qb;  // alias: N*1024 B, qb dead by FFN time
  unsigned char* h8 = xb8;                 // alias: xb8 dead after layer-2 GEMM

  // CSR build
  hipMemsetAsync(deg, 0, (size_t)N*4, stream);
  count_k<<<(E+255)/256, 256, 0, stream>>>(edst, deg, E);
  scan_k<<<1, 1024, 0, stream>>>(deg, rowstart, cursor, N);
  fill_k<<<(E+255)/256, 256, 0, stream>>>(esrc, edst, cursor, csrc, E);

  // all weight transposes (fp8 x64, k-permuted) in one launch
  transpose_all_k<<<1536, 256, 0, stream>>>(Wq, Wk, Wv, Wsk, W1, W2, wtqkvs8, wt1_8, wt2_8);

  const int cvtBlocks = (int)(((size_t)N*512/8 + 255)/256);
  const int rowBlocks = (N + 3)/4;
  const int MB  = (N + 127)/128;   // 157
  const int MB2 = (N + 255)/256;   // 79

  // 2 TransformerConv layers
  cvt8_k<<<cvtBlocks, 256, 0, stream>>>(x0, xb8, encb, (size_t)N*512);
  for (int l = 0; l < 2; ++l){
    gemm8_k<0,512,16,8><<<MB2*16, 256, 0, stream>>>(xb8, wtqkvs8 + (size_t)l*2048*512, N,
        bq + l*512, bk + l*512, bv + l*512, bs + l*512, qb, skipb, kv8, nullptr, nullptr);
    if (l == 0)
      attn_k<0><<<rowBlocks, 256, 0, stream>>>(qb, kv8, skipb, encb, rowstart, csrc,
          nullptr, xb8, nullptr, nullptr, N);
    else
      attn_k<2><<<rowBlocks, 256, 0, stream>>>(qb, kv8, skipb, encb, rowstart, csrc,
          skip, h8, lng, lnb, N);   // fused LN1: skip=f32 h, h8=fp8
  }

  // FFN1: relu(h8 @ W1 + b1) -> fp8 t8 (k-perm)
  gemm8_k<1,512,8,4><<<MB*8, 256, 0, stream>>>(h8, wt1_8, N,
      b1, nullptr, nullptr, nullptr, nullptr, nullptr, t8, nullptr, nullptr);
  // FFN2: t8 @ W2 + b2 + h -> f32 y (in xbuf)
  gemm8_k<2,1024,4,4><<<MB*4, 256, 0, stream>>>(t8, wt2_8, N,
      b2, nullptr, nullptr, nullptr, nullptr, nullptr, nullptr, xbuf, skip);
  // LN2 + enc -> d_out
  ln_k<<<rowBlocks, 256, 0, stream>>>(xbuf, lng, lnb, (float*)d_out, x0, N);
}

// Round 14
// 447.716 us; speedup vs baseline: 1.3484x; 1.3484x over previous
//
#include <hip/hip_runtime.h>

typedef __attribute__((ext_vector_type(8))) short short8;
typedef __attribute__((ext_vector_type(4))) float f32x4;

__device__ __forceinline__ unsigned short f2b(float f){
  union { float f; unsigned u; } x; x.f = f;
  unsigned r = x.u + 0x7fffu + ((x.u >> 16) & 1u);
  return (unsigned short)(r >> 16);
}
__device__ __forceinline__ float b2f(unsigned short v){
  union { unsigned u; float f; } x; x.u = ((unsigned)v) << 16; return x.f;
}

// k-interleave permutation on 8B slots (rotation within each 8-slot/64B group):
// old slot t = S*8 + h*4 + kq  ->  new slot u = S*8 + kq*2 + h.
__device__ __forceinline__ int pslot(int t){
  return (t & ~7) | ((t & 3) << 1) | ((t >> 2) & 1);
}

// ---- fp8 e4m3 encode/decode (HW cvt if available) ----
__device__ __forceinline__ unsigned char enc1(float v){
#if __has_builtin(__builtin_amdgcn_cvt_pk_fp8_f32)
  return (unsigned char)(__builtin_amdgcn_cvt_pk_fp8_f32(v, v, 0, false) & 0xff);
#else
  union{float f;unsigned u;}x; x.f=v;
  unsigned s = x.u >> 31;
  float av = fabsf(v);
  if (av >= 448.f) return (unsigned char)((s<<7)|0x7e);
  if (av < 0.0078125f){ unsigned d=(unsigned)(av*512.f+0.5f); return (unsigned char)((s<<7)|d); }
  unsigned q = x.u & 0x7fffffff;
  q = q + 0x7ffff + ((q>>20)&1);
  int e2 = (int)(q>>23) - 127;
  unsigned m3 = (q>>20)&7;
  if (e2 < -6){ unsigned d=(unsigned)(av*512.f+0.5f); return (unsigned char)((s<<7)|d); }
  return (unsigned char)((s<<7) | ((unsigned)(e2+7)<<3) | m3);
#endif
}
__device__ __forceinline__ unsigned pk4(float a,float b,float c,float d){
#if __has_builtin(__builtin_amdgcn_cvt_pk_fp8_f32)
  int v = __builtin_amdgcn_cvt_pk_fp8_f32(a, b, 0, false);
  v = __builtin_amdgcn_cvt_pk_fp8_f32(c, d, v, true);
  return (unsigned)v;
#else
  return (unsigned)enc1(a) | ((unsigned)enc1(b)<<8) | ((unsigned)enc1(c)<<16) | ((unsigned)enc1(d)<<24);
#endif
}
__device__ __forceinline__ void dec4(unsigned u, float* o){
#if __has_builtin(__builtin_amdgcn_cvt_pk_f32_fp8)
  auto lo = __builtin_amdgcn_cvt_pk_f32_fp8((int)u, false);
  auto hi = __builtin_amdgcn_cvt_pk_f32_fp8((int)u, true);
  o[0]=lo[0]; o[1]=lo[1]; o[2]=hi[0]; o[3]=hi[1];
#else
  #pragma unroll
  for (int j=0;j<4;j++){
    unsigned b = (u >> (8*j)) & 0xffu;
    unsigned s = b >> 7, ex = (b >> 3) & 15u, mn = b & 7u;
    union{unsigned u;float f;} x;
    x.u = ex ? ((s<<31)|((ex+120u)<<23)|(mn<<20)) : (s<<31);
    o[j] = x.f;
  }
#endif
}

// ---------------- CSR build ----------------
__global__ void count_k(const int* __restrict__ dst, int* __restrict__ deg, int E){
  int e = blockIdx.x*256 + threadIdx.x;
  if (e < E) atomicAdd(&deg[dst[e]], 1);
}

__global__ void scan_k(const int* __restrict__ deg, int* __restrict__ rowstart,
                       int* __restrict__ cursor, int n)
{
  __shared__ int wsum[16];
  int tid = threadIdx.x, lane = tid & 63, wv = tid >> 6;
  int CH = (n + 1023) >> 10;
  int b0 = tid * CH; if (b0 > n) b0 = n;
  int bend = b0 + CH; if (bend > n) bend = n;
  int sum = 0;
  for (int i = b0; i < bend; ++i) sum += deg[i];
  int xs = sum;
  #pragma unroll
  for (int o=1;o<64;o<<=1){ int t = __shfl_up(xs, o, 64); if (lane >= o) xs += t; }
  if (lane == 63) wsum[wv] = xs;
  __syncthreads();
  if (tid < 16){
    int w = wsum[tid];
    #pragma unroll
    for (int o=1;o<16;o<<=1){ int t = __shfl_up(w, o, 64); if (tid >= o) w += t; }
    wsum[tid] = w;
  }
  __syncthreads();
  int off = (wv ? wsum[wv-1] : 0) + xs - sum;
  int run = off;
  for (int i = b0; i < bend; ++i){ rowstart[i] = run; cursor[i] = run; run += deg[i]; }
  if (b0 < n && bend == n) rowstart[n] = run;
  if (n == 0 && tid == 0) rowstart[0] = 0;
}

__global__ void fill_k(const int* __restrict__ src, const int* __restrict__ dst,
                       int* __restrict__ cursor, int* __restrict__ csrc, int E){
  int e = blockIdx.x*256 + threadIdx.x;
  if (e < E){
    int p = atomicAdd(&cursor[dst[e]], 1);
    csrc[p] = src[e];
  }
}

// ---------------- fused weight transposes -> fp8 (x64), k-permuted ----------------
__global__ void transpose_all_k(const float* __restrict__ Wq, const float* __restrict__ Wk,
  const float* __restrict__ Wv, const float* __restrict__ Ws,
  const float* __restrict__ W1, const float* __restrict__ W2,
  unsigned char* __restrict__ wtqkvs8, unsigned char* __restrict__ wt1_8,
  unsigned char* __restrict__ wt2_8)
{
  int bid = blockIdx.x;
  const float* src; unsigned char* dst; int r, c, lb;
  if (bid < 1024){
    int j = bid >> 7;        // 0..7
    int l = j >> 2, w = j & 3;
    src = (w==0?Wq : w==1?Wk : w==2?Wv : Ws) + (size_t)l*512*512;
    dst = wtqkvs8 + ((size_t)l*2048 + (size_t)w*512)*512;
    r = 512; c = 512; lb = bid & 127;
  } else if (bid < 1280){ src = W1; dst = wt1_8; r = 512; c = 1024; lb = bid - 1024; }
  else { src = W2; dst = wt2_8; r = 1024; c = 512; lb = bid - 1280; }
  int idx = lb*256 + threadIdx.x;
  int o = idx % c;
  int i0 = (idx / c) << 3;   // k-slot t = i0>>3
  float v[8];
  #pragma unroll
  for (int t=0;t<8;t++) v[t] = 64.f * src[(size_t)(i0+t)*c + o];
  unsigned lo = pk4(v[0],v[1],v[2],v[3]);
  unsigned hi = pk4(v[4],v[5],v[6],v[7]);
  *(unsigned long long*)&dst[(size_t)o*r + pslot(i0>>3)*8] =
      (unsigned long long)lo | ((unsigned long long)hi << 32);
}

// ---------------- f32 -> fp8 k-permuted (x for layer-1 GEMM) + bf16 (enc) ----------------
__global__ void cvt8_k(const float* __restrict__ in, unsigned char* __restrict__ out8,
                       unsigned short* __restrict__ outb, size_t n){
  size_t i = ((size_t)blockIdx.x*256 + threadIdx.x)*8;
  if (i >= n) return;
  const float4* p = (const float4*)(in + i);
  float4 a0 = p[0], a1 = p[1];
  short8 vv;
  ((unsigned short*)&vv)[0] = f2b(a0.x); ((unsigned short*)&vv)[1] = f2b(a0.y);
  ((unsigned short*)&vv)[2] = f2b(a0.z); ((unsigned short*)&vv)[3] = f2b(a0.w);
  ((unsigned short*)&vv)[4] = f2b(a1.x); ((unsigned short*)&vv)[5] = f2b(a1.y);
  ((unsigned short*)&vv)[6] = f2b(a1.z); ((unsigned short*)&vv)[7] = f2b(a1.w);
  *(short8*)&outb[i] = vv;
  unsigned lo = pk4(a0.x,a0.y,a0.z,a0.w);
  unsigned hi = pk4(a1.x,a1.y,a1.z,a1.w);
  size_t op = (i & ~(size_t)511) | ((size_t)pslot((int)((i & 511) >> 3)) << 3);
  *(unsigned long long*)&out8[op] = (unsigned long long)lo | ((unsigned long long)hi<<32);
}

// ---------------- unified fp8 GEMM: A8[M][KC] x Bt8[NN*128][KC], BK=128, k-permuted ----------------
// 128x128 tile, single 32KB-class LDS buffer, serial 2-barrier loop, ~5 blocks/CU (r12-proven optimum).
// MODE 0: QKVS (col<512: bf16 Q; 512..1535: fp8 KV; >=1536: bf16 S)
// MODE 1: FFN1 (bias + relu -> fp8 k-permuted outC[row][1024])
// MODE 2: FFN2 (bias + res -> f32 outF[row][512])
template<int MODE, int KC, int NN>
__global__ __launch_bounds__(256) void gemm8_k(
    const unsigned char* __restrict__ A8,
    const unsigned char* __restrict__ Bt8,
    int M,
    const float* __restrict__ bias0, const float* __restrict__ bias1,
    const float* __restrict__ bias2, const float* __restrict__ bias3,
    unsigned short* __restrict__ qb, unsigned short* __restrict__ skipb,
    unsigned char* __restrict__ outC,
    float* __restrict__ outF, const float* __restrict__ res)
{
  __shared__ __align__(16) unsigned char lA[128*128];
  __shared__ __align__(16) unsigned char lB[128*128];
  const int tid  = threadIdx.x;
  const int lane = tid & 63;
  const int wid  = tid >> 6;

  const int nwg = gridDim.x;
  int id = blockIdx.x;
  int q = nwg >> 3, r = nwg & 7;
  int xc = id & 7, yy = id >> 3;
  int swz = (xc < r ? xc*(q+1) : r*(q+1) + (xc-r)*q) + yy;
  const int bm = (swz / NN) * 128;
  const int bn = (swz % NN) * 128;
  const int wm = (wid >> 1) * 64;
  const int wn = (wid & 1) * 64;

  f32x4 acc[4][4];
  #pragma unroll
  for (int m=0;m<4;m++)
    #pragma unroll
    for (int n=0;n<4;n++) acc[m][n] = (f32x4)0.f;

  const int kq = lane >> 4;          // 0..3 (k-quadrant)

  for (int kt = 0; kt < KC; kt += 128){
    #pragma unroll
    for (int it = 0; it < 4; ++it) {
      int chunk = it*256 + tid;
      int row = chunk >> 3;
      int cin = chunk & 7;
      int scol = (cin ^ (row & 7)) * 16;
      int ga = bm + row; if (ga >= M) ga = M - 1;
      __builtin_amdgcn_global_load_lds(
        (const __attribute__((address_space(1))) void*)(A8 + (size_t)ga*KC + kt + scol),
        (__attribute__((address_space(3))) void*)(&lA[(it*256 + (wid<<6))*16]),
        16, 0, 0);
      __builtin_amdgcn_global_load_lds(
        (const __attribute__((address_space(1))) void*)(Bt8 + (size_t)(bn + row)*KC + kt + scol),
        (__attribute__((address_space(3))) void*)(&lB[(it*256 + (wid<<6))*16]),
        16, 0, 0);
    }
    __syncthreads();
    #pragma unroll
    for (int S = 0; S < 2; ++S){
      ulonglong2 af[4], bfv[4];
      #pragma unroll
      for (int m=0;m<4;m++){
        int rr = wm + m*16 + (lane & 15);
        int c  = (S*4 + kq) ^ (rr & 7);
        af[m] = *(const ulonglong2*)&lA[rr*128 + c*16];
      }
      #pragma unroll
      for (int n=0;n<4;n++){
        int rr = wn + n*16 + (lane & 15);
        int c  = (S*4 + kq) ^ (rr & 7);
        bfv[n] = *(const ulonglong2*)&lB[rr*128 + c*16];
      }
      #pragma unroll
      for (int m=0;m<4;m++)
        #pragma unroll
        for (int n=0;n<4;n++){
          acc[m][n] = __builtin_amdgcn_mfma_f32_16x16x32_fp8_fp8(
              (long)af[m].x, (long)bfv[n].x, acc[m][n], 0,0,0);
          acc[m][n] = __builtin_amdgcn_mfma_f32_16x16x32_fp8_fp8(
              (long)af[m].y, (long)bfv[n].y, acc[m][n], 0,0,0);
        }
    }
    __syncthreads();
  }

  #pragma unroll
  for (int m=0;m<4;m++){
    int row0 = bm + wm + m*16 + ((lane >> 4) << 2);
    #pragma unroll
    for (int n=0;n<4;n++){
      int col = bn + wn + n*16 + (lane & 15);
      float bval;
      if (MODE == 0){
        bval = (col < 512) ? bias0[col]
             : (col < 1024) ? bias1[col-512]
             : (col < 1536) ? bias2[col-1024] : bias3[col-1536];
      } else {
        bval = bias0[col];
      }
      #pragma unroll
      for (int r4=0;r4<4;r4++){
        int row = row0 + r4;
        if (row < M){
          float v = acc[m][n][r4] * 0.015625f + bval;   // /64 weight scale
          if (MODE == 0){
            if (col < 512)       qb[(size_t)row*512 + col] = f2b(v);
            else if (col < 1536) outC[(size_t)row*1024 + (col-512)] = enc1(v);
            else                 skipb[(size_t)row*512 + (col-1536)] = f2b(v);
          } else if (MODE == 1){
            v = fmaxf(v, 0.0f);
            int pc = (pslot(col >> 3) << 3) | (col & 7);
            outC[(size_t)row*1024 + pc] = enc1(v);
          } else {
            v += res[(size_t)row*512 + col];
            outF[(size_t)row*512 + col] = v;
          }
        }
      }
    }
  }
}

// ---------------- attention: one wave per node (static), no-max softmax, 2-deep prefetch ----------------
// OUT 0: write fp8 k-permuted x (layer-2 GEMM input).
// OUT 2: fused LN1 -> write f32 h (outF=skip) + fp8 k-permuted h8 (xout8).
template<int OUT>
__global__ __launch_bounds__(256) void attn_k(
  const unsigned short* __restrict__ qb, const unsigned char* __restrict__ kv8,
  const unsigned short* __restrict__ skipb, const unsigned short* __restrict__ encb,
  const int* __restrict__ rowstart, const int* __restrict__ csrc,
  float* __restrict__ xout, unsigned char* __restrict__ xout8,
  const float* __restrict__ lng, const float* __restrict__ lnb, int N)
{
  int n = blockIdx.x*4 + (threadIdx.x>>6);
  if (n >= N) return;
  int lane = threadIdx.x & 63;

  const short8 qv = *(const short8*)&qb[(size_t)n*512 + lane*8];
  size_t base = (size_t)n*512 + (size_t)lane*8;
  const short8 sv = *(const short8*)&skipb[base];
  const short8 ev = *(const short8*)&encb[base];
  float qf[8];
  #pragma unroll
  for (int j=0;j<8;j++) qf[j] = b2f(((const unsigned short*)&qv)[j]);

  float l = 0.f;
  float acc[8] = {0.f,0.f,0.f,0.f,0.f,0.f,0.f,0.f};
  int e = rowstart[n], e1 = rowstart[n+1];
  if (e < e1){
    int s0 = csrc[e];
    int s1 = (e+1 < e1) ? csrc[e+1] : s0;
    uint2 k0 = *(const uint2*)&kv8[(size_t)s0*1024 + lane*8];
    uint2 v0 = *(const uint2*)&kv8[(size_t)s0*1024 + 512 + lane*8];
    uint2 k1 = *(const uint2*)&kv8[(size_t)s1*1024 + lane*8];
    uint2 v1 = *(const uint2*)&kv8[(size_t)s1*1024 + 512 + lane*8];
    for (; e < e1; ++e){
      int s2 = (e+2 < e1) ? csrc[e+2] : s0;
      uint2 k2 = *(const uint2*)&kv8[(size_t)s2*1024 + lane*8];
      uint2 v2 = *(const uint2*)&kv8[(size_t)s2*1024 + 512 + lane*8];
      float kf[8]; dec4(k0.x, kf); dec4(k0.y, kf+4);
      float dot = 0.f;
      #pragma unroll
      for (int j=0;j<8;j++) dot += qf[j]*kf[j];
      dot += __shfl_xor(dot,1); dot += __shfl_xor(dot,2); dot += __shfl_xor(dot,4);
      float p = __expf(dot * 0.125f);     // 1/sqrt(64); no max shift (bounded logits)
      l += p;
      float vf[8]; dec4(v0.x, vf); dec4(v0.y, vf+4);
      #pragma unroll
      for (int j=0;j<8;j++) acc[j] += p*vf[j];
      k0 = k1; v0 = v1; k1 = k2; v1 = v2;
    }
  }
  float inv = 1.f/(l + 1e-16f);
  float o[8];
  #pragma unroll
  for (int j=0;j<8;j++)
    o[j] = acc[j]*inv + b2f(((const unsigned short*)&sv)[j]) + b2f(((const unsigned short*)&ev)[j]);

  if (OUT == 0){
    unsigned lo = pk4(o[0],o[1],o[2],o[3]);
    unsigned hi = pk4(o[4],o[5],o[6],o[7]);
    size_t op = (size_t)n*512 + ((size_t)pslot(lane) << 3);
    *(unsigned long long*)&xout8[op] = (unsigned long long)lo | ((unsigned long long)hi<<32);
  } else {
    // fused LayerNorm over the row held by this wave
    float s=0.f, ss=0.f;
    #pragma unroll
    for (int j=0;j<8;j++){ s += o[j]; ss += o[j]*o[j]; }
    #pragma unroll
    for (int w=1;w<64;w<<=1){ s += __shfl_xor(s,w); ss += __shfl_xor(ss,w); }
    float mean = s * (1.f/512.f);
    float var  = ss * (1.f/512.f) - mean*mean;
    float rstd = rsqrtf(var + 1e-5f);
    float h[8];
    #pragma unroll
    for (int j=0;j<8;j++){
      int c = lane*8 + j;
      h[j] = (o[j]-mean)*rstd*lng[c] + lnb[c];
    }
    float4* po = (float4*)&xout[base];
    po[0] = make_float4(h[0],h[1],h[2],h[3]);
    po[1] = make_float4(h[4],h[5],h[6],h[7]);
    unsigned lo = pk4(h[0],h[1],h[2],h[3]);
    unsigned hi = pk4(h[4],h[5],h[6],h[7]);
    size_t op = (size_t)n*512 + ((size_t)pslot(lane) << 3);
    *(unsigned long long*)&xout8[op] = (unsigned long long)lo | ((unsigned long long)hi<<32);
  }
}

// ---------------- LayerNorm (wave per row): f32 (ln + addv) -> outF ----------------
__global__ __launch_bounds__(256) void ln_k(const float* __restrict__ x,
  const float* __restrict__ g, const float* __restrict__ b,
  float* __restrict__ outF, const float* __restrict__ addv, int N)
{
  int n = blockIdx.x*4 + (threadIdx.x>>6);
  if (n >= N) return;
  int lane = threadIdx.x & 63;
  size_t base = (size_t)n*512 + (size_t)lane*8;
  const float4* p = (const float4*)(x + base);
  float4 a0 = p[0], a1 = p[1];
  float v[8] = {a0.x,a0.y,a0.z,a0.w,a1.x,a1.y,a1.z,a1.w};
  float s=0.f, ss=0.f;
  #pragma unroll
  for (int j=0;j<8;j++){ s += v[j]; ss += v[j]*v[j]; }
  #pragma unroll
  for (int o=1;o<64;o<<=1){ s += __shfl_xor(s,o); ss += __shfl_xor(ss,o); }
  float mean = s * (1.f/512.f);
  float var  = ss * (1.f/512.f) - mean*mean;
  float rstd = rsqrtf(var + 1e-5f);
  #pragma unroll
  for (int j=0;j<8;j++){
    int c = lane*8 + j;
    float o = (v[j]-mean)*rstd*g[c] + b[c];
    outF[base+j] = o + addv[base+j];
  }
}

extern "C" void kernel_launch(void* const* d_in, const int* in_sizes, int n_in,
                              void* d_out, int out_size, void* d_ws, size_t ws_size,
                              hipStream_t stream)
{
  const float* x0  = (const float*)d_in[0];
  const int*  eidx = (const int*)d_in[1];
  const float* Wq  = (const float*)d_in[4];
  const float* bq  = (const float*)d_in[5];
  const float* Wk  = (const float*)d_in[6];
  const float* bk  = (const float*)d_in[7];
  const float* Wv  = (const float*)d_in[8];
  const float* bv  = (const float*)d_in[9];
  const float* Wsk = (const float*)d_in[10];
  const float* bs  = (const float*)d_in[11];
  const float* W1  = (const float*)d_in[12];
  const float* b1  = (const float*)d_in[13];
  const float* W2  = (const float*)d_in[14];
  const float* b2  = (const float*)d_in[15];
  const float* lng = (const float*)d_in[16];
  const float* lnb = (const float*)d_in[17];

  const int N = in_sizes[0] / 512;
  const int E = in_sizes[1] / 2;
  const int* esrc = eidx;
  const int* edst = eidx + E;

  char* ws = (char*)d_ws;
  size_t off = 0;
  auto alloc = [&](size_t bytes)->char*{
    char* p = ws + off; off = (off + bytes + 255) & ~(size_t)255; return p;
  };
  unsigned char*  wtqkvs8 = (unsigned char*)alloc((size_t)2*2048*512);   // fp8 x64, k-perm
  unsigned char*  wt1_8   = (unsigned char*)alloc((size_t)1024*512);     // fp8 x64, k-perm
  unsigned char*  wt2_8   = (unsigned char*)alloc((size_t)512*1024);     // fp8 x64, k-perm
  unsigned short* qb      = (unsigned short*)alloc((size_t)N*512*2);     // Q bf16
  unsigned char*  kv8     = (unsigned char*)alloc((size_t)N*1024);       // K,V fp8 (natural)
  float*          skip    = (float*)alloc((size_t)N*512*4);              // f32 h after LN1
  float*          xbuf    = (float*)alloc((size_t)N*512*4);              // f32 y after FFN2
  unsigned char*  xb8     = (unsigned char*)alloc((size_t)N*512);        // fp8 x, k-perm
  unsigned short* encb    = (unsigned short*)alloc((size_t)N*512*2);     // bf16 enc
  unsigned short* skipb   = (unsigned short*)alloc((size_t)N*512*2);     // bf16 skip proj
  int* deg      = (int*)alloc((size_t)N*4);
  int* rowstart = (int*)alloc((size_t)(N+1)*4);
  int* cursor   = (int*)alloc((size_t)N*4);
  int* csrc     = (int*)alloc((size_t)E*4);
  unsigned char* t8 = (unsigned char*)qb;  // alias: N*1024 B, qb dead by FFN time
  unsigned char* h8 = xb8;                 // alias: xb8 dead after layer-2 GEMM

  // CSR build
  hipMemsetAsync(deg, 0, (size_t)N*4, stream);
  count_k<<<(E+255)/256, 256, 0, stream>>>(edst, deg, E);
  scan_k<<<1, 1024, 0, stream>>>(deg, rowstart, cursor, N);
  fill_k<<<(E+255)/256, 256, 0, stream>>>(esrc, edst, cursor, csrc, E);

  // all weight transposes (fp8 x64, k-permuted) in one launch
  transpose_all_k<<<1536, 256, 0, stream>>>(Wq, Wk, Wv, Wsk, W1, W2, wtqkvs8, wt1_8, wt2_8);

  const int cvtBlocks = (int)(((size_t)N*512/8 + 255)/256);
  const int rowBlocks = (N + 3)/4;
  const int MB = (N + 127)/128;   // 157

  // 2 TransformerConv layers
  cvt8_k<<<cvtBlocks, 256, 0, stream>>>(x0, xb8, encb, (size_t)N*512);
  for (int l = 0; l < 2; ++l){
    gemm8_k<0,512,16><<<MB*16, 256, 0, stream>>>(xb8, wtqkvs8 + (size_t)l*2048*512, N,
        bq + l*512, bk + l*512, bv + l*512, bs + l*512, qb, skipb, kv8, nullptr, nullptr);
    if (l == 0)
      attn_k<0><<<rowBlocks, 256, 0, stream>>>(qb, kv8, skipb, encb, rowstart, csrc,
          nullptr, xb8, nullptr, nullptr, N);
    else
      attn_k<2><<<rowBlocks, 256, 0, stream>>>(qb, kv8, skipb, encb, rowstart, csrc,
          skip, h8, lng, lnb, N);   // fused LN1: skip=f32 h, h8=fp8
  }

  // FFN1: relu(h8 @ W1 + b1) -> fp8 t8 (k-perm)
  gemm8_k<1,512,8><<<MB*8, 256, 0, stream>>>(h8, wt1_8, N,
      b1, nullptr, nullptr, nullptr, nullptr, nullptr, t8, nullptr, nullptr);
  // FFN2: t8 @ W2 + b2 + h -> f32 y (in xbuf)
  gemm8_k<2,1024,4><<<MB*4, 256, 0, stream>>>(t8, wt2_8, N,
      b2, nullptr, nullptr, nullptr, nullptr, nullptr, nullptr, xbuf, skip);
  // LN2 + enc -> d_out
  ln_k<<<rowBlocks, 256, 0, stream>>>(xbuf, lng, lnb, (float*)d_out, x0, N);
}